// Round 1
// baseline (1212.806 us; speedup 1.0000x reference)
//
#include <hip/hip_runtime.h>
#include <math.h>

#define N_NODES 50000
#define N_EDGES 800000
#define D 128

// ---------------- degree histogram ----------------
__global__ void deg_kernel(const int* __restrict__ dst, float* __restrict__ deg) {
    int e = blockIdx.x * blockDim.x + threadIdx.x;
    if (e < N_EDGES) atomicAdd(&deg[dst[e]], 1.0f);
}

// ---------------- edge-parallel scatter-add ----------------
// 2 edges per 256-thread block; 128 threads handle one edge's 128 features.
__global__ void scatter_kernel(const int* __restrict__ src, const int* __restrict__ dst,
                               const float* __restrict__ x, float* __restrict__ agg) {
    int e = blockIdx.x * 2 + (threadIdx.x >> 7);
    int t = threadIdx.x & 127;
    int s = src[e];
    int d = dst[e];
    atomicAdd(&agg[(size_t)d * D + t], x[(size_t)s * D + t]);
}

// ---------------- mean scale ----------------
__global__ void scale_kernel(float* __restrict__ agg, const float* __restrict__ deg) {
    int idx = blockIdx.x * blockDim.x + threadIdx.x;
    if (idx < N_NODES * D) {
        int n = idx >> 7;
        agg[idx] *= 1.0f / fmaxf(deg[n], 1.0f);
    }
}

// ---------------- fused concat-GEMM ----------------
// out[n,f] = (relu?)( sum_k M1[n,k]*W1[f,k] + sum_k M2[n,k]*W2[f,k] + bias[f] )
// M1,M2: [N,128] row-major. W rows have stride ldW. F_OUT <= 128.
// Tile: 64 nodes x 128 features per 256-thread block; thread computes 4 nodes x 8 features.
template<int F_OUT, bool RELU>
__global__ __launch_bounds__(256) void gemm_fused(
    const float* __restrict__ M1, const float* __restrict__ M2,
    const float* __restrict__ W1, const float* __restrict__ W2, int ldW,
    const float* __restrict__ bias, float* __restrict__ out)
{
    constexpr int BN = 64, BK = 64, LSTR = 68; // LDS row stride in floats (16B-aligned, breaks bank cycles)
    __shared__ float Mlds[BN * LSTR];
    __shared__ float Wlds[128 * LSTR];

    const int tid = threadIdx.x;
    const int tx = tid & 15;   // feature lane: f = tx + 16*i
    const int ty = tid >> 4;   // node group:  n = n0 + ty*4 + j
    const int n0 = blockIdx.x * BN;

    float acc[4][8];
    #pragma unroll
    for (int j = 0; j < 4; j++)
        #pragma unroll
        for (int i = 0; i < 8; i++) acc[j][i] = 0.f;

    #pragma unroll 1
    for (int c = 0; c < 4; c++) {
        const float* Msrc = (c < 2) ? M1 : M2;
        const float* Wsrc = (c < 2) ? W1 : W2;
        const int kbase = (c & 1) * BK;

        // stage M tile: row r = tid/4, 4 threads per row, 16 floats each
        {
            int r = tid >> 2;
            int kq = (tid & 3) * 16;
            int n = n0 + r;
            #pragma unroll
            for (int q = 0; q < 4; q++) {
                float4 v = make_float4(0.f, 0.f, 0.f, 0.f);
                if (n < N_NODES)
                    v = *(const float4*)(Msrc + (size_t)n * D + kbase + kq + q * 4);
                *(float4*)(&Mlds[r * LSTR + kq + q * 4]) = v;
            }
        }
        // stage W tile: row f = tid/2, 2 threads per row, 32 floats each
        {
            int f = tid >> 1;
            int kq = (tid & 1) * 32;
            #pragma unroll
            for (int q = 0; q < 8; q++) {
                float4 v = make_float4(0.f, 0.f, 0.f, 0.f);
                if (f < F_OUT)
                    v = *(const float4*)(Wsrc + (size_t)f * ldW + kbase + kq + q * 4);
                *(float4*)(&Wlds[f * LSTR + kq + q * 4]) = v;
            }
        }
        __syncthreads();

        #pragma unroll
        for (int kk = 0; kk < BK; kk += 4) {
            float4 a4[4], w4[8];
            #pragma unroll
            for (int j = 0; j < 4; j++)
                a4[j] = *(const float4*)(&Mlds[(ty * 4 + j) * LSTR + kk]);
            #pragma unroll
            for (int i = 0; i < 8; i++)
                w4[i] = *(const float4*)(&Wlds[(tx + 16 * i) * LSTR + kk]);
            #pragma unroll
            for (int j = 0; j < 4; j++)
                #pragma unroll
                for (int i = 0; i < 8; i++)
                    acc[j][i] += a4[j].x * w4[i].x + a4[j].y * w4[i].y
                               + a4[j].z * w4[i].z + a4[j].w * w4[i].w;
        }
        __syncthreads();
    }

    #pragma unroll
    for (int j = 0; j < 4; j++) {
        int n = n0 + ty * 4 + j;
        if (n >= N_NODES) continue;
        #pragma unroll
        for (int i = 0; i < 8; i++) {
            int f = tx + 16 * i;
            if (f < F_OUT) {
                float v = acc[j][i] + bias[f];
                if (RELU) v = fmaxf(v, 0.f);
                out[(size_t)n * F_OUT + f] = v;
            }
        }
    }
}

// ---------------- in-place log_softmax over 40 logits ----------------
// one 64-lane wave per node, 4 nodes per block
__global__ void logsoftmax_kernel(float* __restrict__ out) {
    int wave = threadIdx.x >> 6;
    int lane = threadIdx.x & 63;
    int n = blockIdx.x * 4 + wave;
    if (n >= N_NODES) return;
    float v = (lane < 40) ? out[(size_t)n * 40 + lane] : -INFINITY;
    float m = v;
    #pragma unroll
    for (int o = 32; o > 0; o >>= 1) m = fmaxf(m, __shfl_xor(m, o, 64));
    float e = (lane < 40) ? expf(v - m) : 0.f;
    float s = e;
    #pragma unroll
    for (int o = 32; o > 0; o >>= 1) s += __shfl_xor(s, o, 64);
    if (lane < 40) out[(size_t)n * 40 + lane] = v - m - logf(s);
}

extern "C" void kernel_launch(void* const* d_in, const int* in_sizes, int n_in,
                              void* d_out, int out_size, void* d_ws, size_t ws_size,
                              hipStream_t stream) {
    const float* x     = (const float*)d_in[0];
    const int*   ei    = (const int*)d_in[1];
    const int*   src   = ei;             // edge_index[0], length E
    const int*   dst   = ei + N_EDGES;   // edge_index[1]
    const float* W1_l  = (const float*)d_in[2];
    const float* b1_l  = (const float*)d_in[3];
    const float* W1_r  = (const float*)d_in[4];
    const float* W2_l  = (const float*)d_in[5];
    const float* b2_l  = (const float*)d_in[6];
    const float* W2_r  = (const float*)d_in[7];
    const float* W_lin = (const float*)d_in[8];
    const float* b_lin = (const float*)d_in[9];
    float* out = (float*)d_out;

    float* agg = (float*)d_ws;                       // 50000*128 f32
    float* h1  = agg + (size_t)N_NODES * D;          // 50000*128 f32
    float* h2  = h1  + (size_t)N_NODES * D;          // 50000*128 f32
    float* deg = h2  + (size_t)N_NODES * D;          // 50000 f32

    const size_t aggB = (size_t)N_NODES * D * sizeof(float);

    hipMemsetAsync(deg, 0, N_NODES * sizeof(float), stream);
    hipMemsetAsync(agg, 0, aggB, stream);
    deg_kernel<<<(N_EDGES + 255) / 256, 256, 0, stream>>>(dst, deg);

    // ---- layer 1 ----
    scatter_kernel<<<N_EDGES / 2, 256, 0, stream>>>(src, dst, x, agg);
    scale_kernel<<<(N_NODES * D + 255) / 256, 256, 0, stream>>>(agg, deg);
    gemm_fused<128, true><<<(N_NODES + 63) / 64, 256, 0, stream>>>(
        agg, x, W1_l, W1_r, 128, b1_l, h1);

    // ---- layer 2 ----
    hipMemsetAsync(agg, 0, aggB, stream);
    scatter_kernel<<<N_EDGES / 2, 256, 0, stream>>>(src, dst, h1, agg);
    scale_kernel<<<(N_NODES * D + 255) / 256, 256, 0, stream>>>(agg, deg);
    gemm_fused<128, true><<<(N_NODES + 63) / 64, 256, 0, stream>>>(
        agg, h1, W2_l, W2_r, 128, b2_l, h2);

    // ---- final linear + log_softmax ----
    gemm_fused<40, false><<<(N_NODES + 63) / 64, 256, 0, stream>>>(
        h1, h2, W_lin, W_lin + 128, 256, b_lin, out);
    logsoftmax_kernel<<<(N_NODES + 3) / 4, 256, 0, stream>>>(out);
}

// Round 2
// 682.609 us; speedup vs baseline: 1.7767x; 1.7767x over previous
//
#include <hip/hip_runtime.h>
#include <math.h>

#define N_NODES 50000
#define N_EDGES 800000
#define D 128

// ---------------- degree histogram (int) ----------------
__global__ void deg_kernel(const int* __restrict__ dst, int* __restrict__ deg) {
    int e = blockIdx.x * blockDim.x + threadIdx.x;
    if (e < N_EDGES) atomicAdd(&deg[dst[e]], 1);
}

// ---------------- single-block prefix sum (wave scan) ----------------
__global__ __launch_bounds__(1024) void scan_kernel(const int* __restrict__ deg,
                                                    int* __restrict__ rowptr,
                                                    int* __restrict__ cursor) {
    __shared__ int wtot[16];
    __shared__ int s_carry;
    int tid = threadIdx.x;
    int lane = tid & 63, wv = tid >> 6;
    if (tid == 0) s_carry = 0;
    __syncthreads();
    for (int base = 0; base < N_NODES; base += 1024) {
        int idx = base + tid;
        int v = (idx < N_NODES) ? deg[idx] : 0;
        int scan = v;
        #pragma unroll
        for (int o = 1; o < 64; o <<= 1) {
            int t = __shfl_up(scan, o, 64);
            if (lane >= o) scan += t;
        }
        if (lane == 63) wtot[wv] = scan;
        __syncthreads();
        int woff = 0;
        #pragma unroll
        for (int w = 0; w < 16; w++) woff += (w < wv) ? wtot[w] : 0;
        int carry = s_carry;
        int excl = carry + woff + scan - v;
        if (idx < N_NODES) { rowptr[idx] = excl; cursor[idx] = excl; }
        __syncthreads();
        if (tid == 0) {
            int tot = 0;
            #pragma unroll
            for (int w = 0; w < 16; w++) tot += wtot[w];
            s_carry = carry + tot;
        }
        __syncthreads();
    }
    if (tid == 0) rowptr[N_NODES] = s_carry;
}

// ---------------- bucket edges by dst (counting sort) ----------------
__global__ void bucket_kernel(const int* __restrict__ src, const int* __restrict__ dst,
                              int* __restrict__ cursor, int* __restrict__ srcs_sorted) {
    int e = blockIdx.x * blockDim.x + threadIdx.x;
    if (e < N_EDGES) {
        int pos = atomicAdd(&cursor[dst[e]], 1);
        srcs_sorted[pos] = src[e];
    }
}

// ---------------- CSR gather + mean (one wave per node) ----------------
__global__ __launch_bounds__(256) void gather_mean(const int* __restrict__ srcs,
                                                   const int* __restrict__ rowptr,
                                                   const float* __restrict__ x,
                                                   float* __restrict__ agg) {
    int node = blockIdx.x * 4 + (threadIdx.x >> 6);
    if (node >= N_NODES) return;
    int lane = threadIdx.x & 63;
    int beg = rowptr[node], end = rowptr[node + 1];
    float2 a0 = {0.f, 0.f}, a1 = {0.f, 0.f}, a2 = {0.f, 0.f}, a3 = {0.f, 0.f};
    int i = beg;
    for (; i + 4 <= end; i += 4) {
        int s0 = srcs[i], s1 = srcs[i + 1], s2 = srcs[i + 2], s3 = srcs[i + 3];
        float2 v0 = *(const float2*)(x + (size_t)s0 * D + lane * 2);
        float2 v1 = *(const float2*)(x + (size_t)s1 * D + lane * 2);
        float2 v2 = *(const float2*)(x + (size_t)s2 * D + lane * 2);
        float2 v3 = *(const float2*)(x + (size_t)s3 * D + lane * 2);
        a0.x += v0.x; a0.y += v0.y;
        a1.x += v1.x; a1.y += v1.y;
        a2.x += v2.x; a2.y += v2.y;
        a3.x += v3.x; a3.y += v3.y;
    }
    for (; i < end; i++) {
        int s = srcs[i];
        float2 v = *(const float2*)(x + (size_t)s * D + lane * 2);
        a0.x += v.x; a0.y += v.y;
    }
    float2 r;
    r.x = (a0.x + a1.x) + (a2.x + a3.x);
    r.y = (a0.y + a1.y) + (a2.y + a3.y);
    float inv = 1.0f / fmaxf((float)(end - beg), 1.0f);
    r.x *= inv; r.y *= inv;
    *(float2*)(agg + (size_t)node * D + lane * 2) = r;
}

// ---------------- fused concat-GEMM ----------------
// out[n,f] = (relu?)( M1[n,:]·W1[f,:] + M2[n,:]·W2[f,:] + bias[f] )
template<int F_OUT, bool RELU>
__global__ __launch_bounds__(256) void gemm_fused(
    const float* __restrict__ M1, const float* __restrict__ M2,
    const float* __restrict__ W1, const float* __restrict__ W2, int ldW,
    const float* __restrict__ bias, float* __restrict__ out)
{
    constexpr int BN = 64, BK = 64, LSTR = 68;
    __shared__ float Mlds[BN * LSTR];
    __shared__ float Wlds[128 * LSTR];

    const int tid = threadIdx.x;
    const int tx = tid & 15;
    const int ty = tid >> 4;
    const int n0 = blockIdx.x * BN;

    float acc[4][8];
    #pragma unroll
    for (int j = 0; j < 4; j++)
        #pragma unroll
        for (int i = 0; i < 8; i++) acc[j][i] = 0.f;

    #pragma unroll 1
    for (int c = 0; c < 4; c++) {
        const float* Msrc = (c < 2) ? M1 : M2;
        const float* Wsrc = (c < 2) ? W1 : W2;
        const int kbase = (c & 1) * BK;

        {
            int r = tid >> 2;
            int kq = (tid & 3) * 16;
            int n = n0 + r;
            #pragma unroll
            for (int q = 0; q < 4; q++) {
                float4 v = make_float4(0.f, 0.f, 0.f, 0.f);
                if (n < N_NODES)
                    v = *(const float4*)(Msrc + (size_t)n * D + kbase + kq + q * 4);
                *(float4*)(&Mlds[r * LSTR + kq + q * 4]) = v;
            }
        }
        {
            int f = tid >> 1;
            int kq = (tid & 1) * 32;
            #pragma unroll
            for (int q = 0; q < 8; q++) {
                float4 v = make_float4(0.f, 0.f, 0.f, 0.f);
                if (f < F_OUT)
                    v = *(const float4*)(Wsrc + (size_t)f * ldW + kbase + kq + q * 4);
                *(float4*)(&Wlds[f * LSTR + kq + q * 4]) = v;
            }
        }
        __syncthreads();

        #pragma unroll
        for (int kk = 0; kk < BK; kk += 4) {
            float4 a4[4], w4[8];
            #pragma unroll
            for (int j = 0; j < 4; j++)
                a4[j] = *(const float4*)(&Mlds[(ty * 4 + j) * LSTR + kk]);
            #pragma unroll
            for (int i = 0; i < 8; i++)
                w4[i] = *(const float4*)(&Wlds[(tx + 16 * i) * LSTR + kk]);
            #pragma unroll
            for (int j = 0; j < 4; j++)
                #pragma unroll
                for (int i = 0; i < 8; i++)
                    acc[j][i] += a4[j].x * w4[i].x + a4[j].y * w4[i].y
                               + a4[j].z * w4[i].z + a4[j].w * w4[i].w;
        }
        __syncthreads();
    }

    #pragma unroll
    for (int j = 0; j < 4; j++) {
        int n = n0 + ty * 4 + j;
        if (n >= N_NODES) continue;
        #pragma unroll
        for (int i = 0; i < 8; i++) {
            int f = tx + 16 * i;
            if (f < F_OUT) {
                float v = acc[j][i] + bias[f];
                if (RELU) v = fmaxf(v, 0.f);
                out[(size_t)n * F_OUT + f] = v;
            }
        }
    }
}

// ---------------- in-place log_softmax over 40 logits ----------------
__global__ void logsoftmax_kernel(float* __restrict__ out) {
    int wave = threadIdx.x >> 6;
    int lane = threadIdx.x & 63;
    int n = blockIdx.x * 4 + wave;
    if (n >= N_NODES) return;
    float v = (lane < 40) ? out[(size_t)n * 40 + lane] : -INFINITY;
    float m = v;
    #pragma unroll
    for (int o = 32; o > 0; o >>= 1) m = fmaxf(m, __shfl_xor(m, o, 64));
    float e = (lane < 40) ? expf(v - m) : 0.f;
    float s = e;
    #pragma unroll
    for (int o = 32; o > 0; o >>= 1) s += __shfl_xor(s, o, 64);
    if (lane < 40) out[(size_t)n * 40 + lane] = v - m - logf(s);
}

extern "C" void kernel_launch(void* const* d_in, const int* in_sizes, int n_in,
                              void* d_out, int out_size, void* d_ws, size_t ws_size,
                              hipStream_t stream) {
    const float* x     = (const float*)d_in[0];
    const int*   ei    = (const int*)d_in[1];
    const int*   src   = ei;
    const int*   dst   = ei + N_EDGES;
    const float* W1_l  = (const float*)d_in[2];
    const float* b1_l  = (const float*)d_in[3];
    const float* W1_r  = (const float*)d_in[4];
    const float* W2_l  = (const float*)d_in[5];
    const float* b2_l  = (const float*)d_in[6];
    const float* W2_r  = (const float*)d_in[7];
    const float* W_lin = (const float*)d_in[8];
    const float* b_lin = (const float*)d_in[9];
    float* out = (float*)d_out;

    float* agg = (float*)d_ws;                         // 50000*128 f32
    float* h1  = agg + (size_t)N_NODES * D;            // 50000*128 f32
    float* h2  = h1  + (size_t)N_NODES * D;            // 50000*128 f32
    int*   deg    = (int*)(h2 + (size_t)N_NODES * D);  // 50000 int
    int*   rowptr = deg + N_NODES;                     // 50001 int
    int*   cursor = rowptr + N_NODES + 1;              // 50000 int
    int*   srcs_sorted = cursor + N_NODES;             // 800000 int

    // ---- CSR build (once; reused by both layers) ----
    hipMemsetAsync(deg, 0, N_NODES * sizeof(int), stream);
    deg_kernel<<<(N_EDGES + 255) / 256, 256, 0, stream>>>(dst, deg);
    scan_kernel<<<1, 1024, 0, stream>>>(deg, rowptr, cursor);
    bucket_kernel<<<(N_EDGES + 255) / 256, 256, 0, stream>>>(src, dst, cursor, srcs_sorted);

    // ---- layer 1 ----
    gather_mean<<<(N_NODES + 3) / 4, 256, 0, stream>>>(srcs_sorted, rowptr, x, agg);
    gemm_fused<128, true><<<(N_NODES + 63) / 64, 256, 0, stream>>>(
        agg, x, W1_l, W1_r, 128, b1_l, h1);

    // ---- layer 2 ----
    gather_mean<<<(N_NODES + 3) / 4, 256, 0, stream>>>(srcs_sorted, rowptr, h1, agg);
    gemm_fused<128, true><<<(N_NODES + 63) / 64, 256, 0, stream>>>(
        agg, h1, W2_l, W2_r, 128, b2_l, h2);

    // ---- final linear + log_softmax ----
    gemm_fused<40, false><<<(N_NODES + 63) / 64, 256, 0, stream>>>(
        h1, h2, W_lin, W_lin + 128, 256, b_lin, out);
    logsoftmax_kernel<<<(N_NODES + 3) / 4, 256, 0, stream>>>(out);
}

// Round 4
// 515.772 us; speedup vs baseline: 2.3514x; 1.3235x over previous
//
#include <hip/hip_runtime.h>
#include <math.h>

#define N_NODES 50000
#define N_EDGES 800000
#define D 128

typedef __attribute__((ext_vector_type(8))) short bf16x8;
typedef __attribute__((ext_vector_type(4))) float f32x4;

static __device__ __forceinline__ unsigned short f2bf(float f) {
    unsigned int u = __float_as_uint(f);
    u = (u + 0x7fffu + ((u >> 16) & 1u)) >> 16;
    return (unsigned short)u;
}
static __device__ __forceinline__ float bf2f(unsigned short h) {
    return __uint_as_float(((unsigned int)h) << 16);
}

// ---------------- weight split-cast: [F,128]+[F,128] -> hi/lo [F,256] ----------------
__global__ void cast_cat_kernel(const float* __restrict__ A, const float* __restrict__ B,
                                unsigned short* __restrict__ hi, unsigned short* __restrict__ lo) {
    int f = blockIdx.x, t = threadIdx.x;           // grid=128, block=128
    float va = A[f * 128 + t], vb = B[f * 128 + t];
    unsigned short ha = f2bf(va), hb = f2bf(vb);
    hi[f * 256 + t]       = ha;
    hi[f * 256 + 128 + t] = hb;
    lo[f * 256 + t]       = f2bf(va - bf2f(ha));
    lo[f * 256 + 128 + t] = f2bf(vb - bf2f(hb));
}

// W_lin [40,256] -> hi/lo [48,256] zero-padded. grid=48, block=256
__global__ void cast_wlin_kernel(const float* __restrict__ W,
                                 unsigned short* __restrict__ hi, unsigned short* __restrict__ lo) {
    int f = blockIdx.x, t = threadIdx.x;
    float v = (f < 40) ? W[f * 256 + t] : 0.f;
    unsigned short h = f2bf(v);
    hi[f * 256 + t] = h;
    lo[f * 256 + t] = f2bf(v - bf2f(h));
}

// ---------------- degree histogram (int) ----------------
__global__ void deg_kernel(const int* __restrict__ dst, int* __restrict__ deg) {
    int e = blockIdx.x * blockDim.x + threadIdx.x;
    if (e < N_EDGES) atomicAdd(&deg[dst[e]], 1);
}

// ---------------- single-block prefix sum ----------------
__global__ __launch_bounds__(1024) void scan_kernel(const int* __restrict__ deg,
                                                    int* __restrict__ rowptr,
                                                    int* __restrict__ cursor) {
    __shared__ int wtot[16];
    __shared__ int s_carry;
    int tid = threadIdx.x;
    int lane = tid & 63, wv = tid >> 6;
    if (tid == 0) s_carry = 0;
    __syncthreads();
    for (int base = 0; base < N_NODES; base += 1024) {
        int idx = base + tid;
        int v = (idx < N_NODES) ? deg[idx] : 0;
        int scan = v;
        #pragma unroll
        for (int o = 1; o < 64; o <<= 1) {
            int t = __shfl_up(scan, o, 64);
            if (lane >= o) scan += t;
        }
        if (lane == 63) wtot[wv] = scan;
        __syncthreads();
        int woff = 0;
        #pragma unroll
        for (int w = 0; w < 16; w++) woff += (w < wv) ? wtot[w] : 0;
        int carry = s_carry;
        int excl = carry + woff + scan - v;
        if (idx < N_NODES) { rowptr[idx] = excl; cursor[idx] = excl; }
        __syncthreads();
        if (tid == 0) {
            int tot = 0;
            #pragma unroll
            for (int w = 0; w < 16; w++) tot += wtot[w];
            s_carry = carry + tot;
        }
        __syncthreads();
    }
    if (tid == 0) rowptr[N_NODES] = s_carry;
}

// ---------------- bucket edges by dst ----------------
__global__ void bucket_kernel(const int* __restrict__ src, const int* __restrict__ dst,
                              int* __restrict__ cursor, int* __restrict__ srcs_sorted) {
    int e = blockIdx.x * blockDim.x + threadIdx.x;
    if (e < N_EDGES) {
        int pos = atomicAdd(&cursor[dst[e]], 1);
        srcs_sorted[pos] = src[e];
    }
}

// ---------------- CSR gather + mean, fp32 (one wave per node) ----------------
__global__ __launch_bounds__(256) void gather_mean(const int* __restrict__ srcs,
                                                   const int* __restrict__ rowptr,
                                                   const float* __restrict__ x,
                                                   float* __restrict__ agg) {
    int node = blockIdx.x * 4 + (threadIdx.x >> 6);
    if (node >= N_NODES) return;
    int lane = threadIdx.x & 63;
    int beg = rowptr[node], end = rowptr[node + 1];
    float2 a0 = {0.f, 0.f}, a1 = {0.f, 0.f}, a2 = {0.f, 0.f}, a3 = {0.f, 0.f};
    int i = beg;
    for (; i + 4 <= end; i += 4) {
        int s0 = srcs[i], s1 = srcs[i + 1], s2 = srcs[i + 2], s3 = srcs[i + 3];
        float2 v0 = *(const float2*)(x + (size_t)s0 * D + lane * 2);
        float2 v1 = *(const float2*)(x + (size_t)s1 * D + lane * 2);
        float2 v2 = *(const float2*)(x + (size_t)s2 * D + lane * 2);
        float2 v3 = *(const float2*)(x + (size_t)s3 * D + lane * 2);
        a0.x += v0.x; a0.y += v0.y;
        a1.x += v1.x; a1.y += v1.y;
        a2.x += v2.x; a2.y += v2.y;
        a3.x += v3.x; a3.y += v3.y;
    }
    for (; i < end; i++) {
        float2 v = *(const float2*)(x + (size_t)srcs[i] * D + lane * 2);
        a0.x += v.x; a0.y += v.y;
    }
    float2 r;
    r.x = (a0.x + a1.x) + (a2.x + a3.x);
    r.y = (a0.y + a1.y) + (a2.y + a3.y);
    float inv = 1.0f / fmaxf((float)(end - beg), 1.0f);
    r.x *= inv; r.y *= inv;
    *(float2*)(agg + (size_t)node * D + lane * 2) = r;
}

// ---------------- split-bf16 MFMA GEMM (no LDS) ----------------
// out[n,f] = act( [M1|M2][n,:] . W[f,:] + bias[f] ), K=256, fp32 in/out.
// A split in-register into hi+lo bf16; W pre-split. 3 MFMA chains recover ~fp32 accuracy.
template<int NT, bool RELU>
__global__ __launch_bounds__(256) void mfma_gemm(
    const float* __restrict__ M1, const float* __restrict__ M2,
    const unsigned short* __restrict__ Whi, const unsigned short* __restrict__ Wlo,
    const float* __restrict__ bias, float* __restrict__ out, int F_OUT)
{
    int wave = threadIdx.x >> 6, lane = threadIdx.x & 63;
    int m = lane & 15, quad = lane >> 4;
    int node_base = (blockIdx.x * 4 + wave) * 16;
    if (node_base >= N_NODES) return;
    int nodec = min(node_base + m, N_NODES - 1);

    bf16x8 ahi[8], alo[8];
    {
        const float* m1row = M1 + (size_t)nodec * D + quad * 8;
        const float* m2row = M2 + (size_t)nodec * D + quad * 8;
        #pragma unroll
        for (int half = 0; half < 2; half++) {
            const float* row = half ? m2row : m1row;
            #pragma unroll
            for (int ks = 0; ks < 4; ks++) {
                float4 v0 = *(const float4*)(row + ks * 32);
                float4 v1 = *(const float4*)(row + ks * 32 + 4);
                float vv[8] = {v0.x, v0.y, v0.z, v0.w, v1.x, v1.y, v1.z, v1.w};
                int idx = half * 4 + ks;
                #pragma unroll
                for (int j = 0; j < 8; j++) {
                    unsigned short h = f2bf(vv[j]);
                    ahi[idx][j] = (short)h;
                    alo[idx][j] = (short)f2bf(vv[j] - bf2f(h));
                }
            }
        }
    }

    #pragma unroll
    for (int nt = 0; nt < NT; nt++) {
        int f = nt * 16 + m;
        const unsigned short* whirow = Whi + (size_t)f * 256 + quad * 8;
        const unsigned short* wlorow = Wlo + (size_t)f * 256 + quad * 8;
        f32x4 acc0 = {0.f, 0.f, 0.f, 0.f};
        f32x4 acc1 = {0.f, 0.f, 0.f, 0.f};
        f32x4 acc2 = {0.f, 0.f, 0.f, 0.f};
        #pragma unroll
        for (int ks = 0; ks < 8; ks++) {
            bf16x8 bh = *(const bf16x8*)(whirow + ks * 32);
            bf16x8 bl = *(const bf16x8*)(wlorow + ks * 32);
            acc0 = __builtin_amdgcn_mfma_f32_16x16x32_bf16(ahi[ks], bh, acc0, 0, 0, 0);
            acc1 = __builtin_amdgcn_mfma_f32_16x16x32_bf16(ahi[ks], bl, acc1, 0, 0, 0);
            acc2 = __builtin_amdgcn_mfma_f32_16x16x32_bf16(alo[ks], bh, acc2, 0, 0, 0);
        }
        float bv = (f < F_OUT) ? bias[f] : 0.f;
        #pragma unroll
        for (int r = 0; r < 4; r++) {
            int nrow = node_base + quad * 4 + r;
            if (nrow >= N_NODES || f >= F_OUT) continue;
            float v = (acc0[r] + (acc1[r] + acc2[r])) + bv;
            if (RELU) v = fmaxf(v, 0.f);
            out[(size_t)nrow * F_OUT + f] = v;
        }
    }
}

// ---------------- in-place log_softmax over 40 logits ----------------
__global__ void logsoftmax_kernel(float* __restrict__ out) {
    int wave = threadIdx.x >> 6;
    int lane = threadIdx.x & 63;
    int n = blockIdx.x * 4 + wave;
    if (n >= N_NODES) return;
    float v = (lane < 40) ? out[(size_t)n * 40 + lane] : -INFINITY;
    float m = v;
    #pragma unroll
    for (int o = 32; o > 0; o >>= 1) m = fmaxf(m, __shfl_xor(m, o, 64));
    float e = (lane < 40) ? expf(v - m) : 0.f;
    float s = e;
    #pragma unroll
    for (int o = 32; o > 0; o >>= 1) s += __shfl_xor(s, o, 64);
    if (lane < 40) out[(size_t)n * 40 + lane] = v - m - logf(s);
}

extern "C" void kernel_launch(void* const* d_in, const int* in_sizes, int n_in,
                              void* d_out, int out_size, void* d_ws, size_t ws_size,
                              hipStream_t stream) {
    const float* x     = (const float*)d_in[0];
    const int*   ei    = (const int*)d_in[1];
    const int*   src   = ei;
    const int*   dst   = ei + N_EDGES;
    const float* W1_l  = (const float*)d_in[2];
    const float* b1_l  = (const float*)d_in[3];
    const float* W1_r  = (const float*)d_in[4];
    const float* W2_l  = (const float*)d_in[5];
    const float* b2_l  = (const float*)d_in[6];
    const float* W2_r  = (const float*)d_in[7];
    const float* W_lin = (const float*)d_in[8];
    const float* b_lin = (const float*)d_in[9];
    float* out = (float*)d_out;

    const size_t nd = (size_t)N_NODES * D;
    float* agg = (float*)d_ws;
    float* h1  = agg + nd;
    float* h2  = h1 + nd;
    unsigned short* W1hi = (unsigned short*)(h2 + nd);  // 128*256 bf16 each
    unsigned short* W1lo = W1hi + 128 * 256;
    unsigned short* W2hi = W1lo + 128 * 256;
    unsigned short* W2lo = W2hi + 128 * 256;
    unsigned short* WLhi = W2lo + 128 * 256;            // 48*256
    unsigned short* WLlo = WLhi + 48 * 256;
    int* deg    = (int*)(WLlo + 48 * 256);
    int* rowptr = deg + N_NODES;
    int* cursor = rowptr + N_NODES + 1;
    int* srcs_sorted = cursor + N_NODES;

    // ---- CSR build (reused by both layers) ----
    hipMemsetAsync(deg, 0, N_NODES * sizeof(int), stream);
    deg_kernel<<<(N_EDGES + 255) / 256, 256, 0, stream>>>(dst, deg);
    scan_kernel<<<1, 1024, 0, stream>>>(deg, rowptr, cursor);
    bucket_kernel<<<(N_EDGES + 255) / 256, 256, 0, stream>>>(src, dst, cursor, srcs_sorted);

    // ---- weight split-casts ----
    cast_cat_kernel<<<128, 128, 0, stream>>>(W1_l, W1_r, W1hi, W1lo);
    cast_cat_kernel<<<128, 128, 0, stream>>>(W2_l, W2_r, W2hi, W2lo);
    cast_wlin_kernel<<<48, 256, 0, stream>>>(W_lin, WLhi, WLlo);

    const int gblk = (N_NODES + 63) / 64;

    // ---- layer 1 ----
    gather_mean<<<(N_NODES + 3) / 4, 256, 0, stream>>>(srcs_sorted, rowptr, x, agg);
    mfma_gemm<8, true><<<gblk, 256, 0, stream>>>(agg, x, W1hi, W1lo, b1_l, h1, 128);

    // ---- layer 2 ----
    gather_mean<<<(N_NODES + 3) / 4, 256, 0, stream>>>(srcs_sorted, rowptr, h1, agg);
    mfma_gemm<8, true><<<gblk, 256, 0, stream>>>(agg, h1, W2hi, W2lo, b2_l, h2, 128);

    // ---- final linear + log_softmax ----
    mfma_gemm<3, false><<<gblk, 256, 0, stream>>>(h1, h2, WLhi, WLlo, b_lin, out, 40);
    logsoftmax_kernel<<<(N_NODES + 3) / 4, 256, 0, stream>>>(out);
}

// Round 5
// 492.640 us; speedup vs baseline: 2.4619x; 1.0470x over previous
//
#include <hip/hip_runtime.h>
#include <math.h>

#define N_NODES 50000
#define N_EDGES 800000
#define D 128

typedef __attribute__((ext_vector_type(8))) short bf16x8;
typedef __attribute__((ext_vector_type(4))) float f32x4;

static __device__ __forceinline__ unsigned short f2bf(float f) {
    unsigned int u = __float_as_uint(f);
    u = (u + 0x7fffu + ((u >> 16) & 1u)) >> 16;
    return (unsigned short)u;
}
static __device__ __forceinline__ float bf2f(unsigned short h) {
    return __uint_as_float(((unsigned int)h) << 16);
}

// ---------------- weight split-cast: [F,128]+[F,128] -> hi/lo [F,256] ----------------
__global__ void cast_cat_kernel(const float* __restrict__ A, const float* __restrict__ B,
                                unsigned short* __restrict__ hi, unsigned short* __restrict__ lo) {
    int f = blockIdx.x, t = threadIdx.x;           // grid=128, block=128
    float va = A[f * 128 + t], vb = B[f * 128 + t];
    unsigned short ha = f2bf(va), hb = f2bf(vb);
    hi[f * 256 + t]       = ha;
    hi[f * 256 + 128 + t] = hb;
    lo[f * 256 + t]       = f2bf(va - bf2f(ha));
    lo[f * 256 + 128 + t] = f2bf(vb - bf2f(hb));
}

// W_lin [40,256] -> hi/lo [48,256] zero-padded. grid=48, block=256
__global__ void cast_wlin_kernel(const float* __restrict__ W,
                                 unsigned short* __restrict__ hi, unsigned short* __restrict__ lo) {
    int f = blockIdx.x, t = threadIdx.x;
    float v = (f < 40) ? W[f * 256 + t] : 0.f;
    unsigned short h = f2bf(v);
    hi[f * 256 + t] = h;
    lo[f * 256 + t] = f2bf(v - bf2f(h));
}

// ---------------- degree histogram (int) ----------------
__global__ void deg_kernel(const int* __restrict__ dst, int* __restrict__ deg) {
    int e = blockIdx.x * blockDim.x + threadIdx.x;
    if (e < N_EDGES) atomicAdd(&deg[dst[e]], 1);
}

// ---------------- single-block prefix sum ----------------
__global__ __launch_bounds__(1024) void scan_kernel(const int* __restrict__ deg,
                                                    int* __restrict__ rowptr,
                                                    int* __restrict__ cursor) {
    __shared__ int wtot[16];
    __shared__ int s_carry;
    int tid = threadIdx.x;
    int lane = tid & 63, wv = tid >> 6;
    if (tid == 0) s_carry = 0;
    __syncthreads();
    for (int base = 0; base < N_NODES; base += 1024) {
        int idx = base + tid;
        int v = (idx < N_NODES) ? deg[idx] : 0;
        int scan = v;
        #pragma unroll
        for (int o = 1; o < 64; o <<= 1) {
            int t = __shfl_up(scan, o, 64);
            if (lane >= o) scan += t;
        }
        if (lane == 63) wtot[wv] = scan;
        __syncthreads();
        int woff = 0;
        #pragma unroll
        for (int w = 0; w < 16; w++) woff += (w < wv) ? wtot[w] : 0;
        int carry = s_carry;
        int excl = carry + woff + scan - v;
        if (idx < N_NODES) { rowptr[idx] = excl; cursor[idx] = excl; }
        __syncthreads();
        if (tid == 0) {
            int tot = 0;
            #pragma unroll
            for (int w = 0; w < 16; w++) tot += wtot[w];
            s_carry = carry + tot;
        }
        __syncthreads();
    }
    if (tid == 0) rowptr[N_NODES] = s_carry;
}

// ---------------- bucket edges by dst ----------------
__global__ void bucket_kernel(const int* __restrict__ src, const int* __restrict__ dst,
                              int* __restrict__ cursor, int* __restrict__ srcs_sorted) {
    int e = blockIdx.x * blockDim.x + threadIdx.x;
    if (e < N_EDGES) {
        int pos = atomicAdd(&cursor[dst[e]], 1);
        srcs_sorted[pos] = src[e];
    }
}

// ---------------- CSR gather + mean, fp32 (one wave per node) ----------------
__global__ __launch_bounds__(256) void gather_mean(const int* __restrict__ srcs,
                                                   const int* __restrict__ rowptr,
                                                   const float* __restrict__ x,
                                                   float* __restrict__ agg) {
    int node = blockIdx.x * 4 + (threadIdx.x >> 6);
    if (node >= N_NODES) return;
    int lane = threadIdx.x & 63;
    int beg = rowptr[node], end = rowptr[node + 1];
    float2 a0 = {0.f, 0.f}, a1 = {0.f, 0.f}, a2 = {0.f, 0.f}, a3 = {0.f, 0.f};
    int i = beg;
    for (; i + 4 <= end; i += 4) {
        int s0 = srcs[i], s1 = srcs[i + 1], s2 = srcs[i + 2], s3 = srcs[i + 3];
        float2 v0 = *(const float2*)(x + (size_t)s0 * D + lane * 2);
        float2 v1 = *(const float2*)(x + (size_t)s1 * D + lane * 2);
        float2 v2 = *(const float2*)(x + (size_t)s2 * D + lane * 2);
        float2 v3 = *(const float2*)(x + (size_t)s3 * D + lane * 2);
        a0.x += v0.x; a0.y += v0.y;
        a1.x += v1.x; a1.y += v1.y;
        a2.x += v2.x; a2.y += v2.y;
        a3.x += v3.x; a3.y += v3.y;
    }
    for (; i < end; i++) {
        float2 v = *(const float2*)(x + (size_t)srcs[i] * D + lane * 2);
        a0.x += v.x; a0.y += v.y;
    }
    float2 r;
    r.x = (a0.x + a1.x) + (a2.x + a3.x);
    r.y = (a0.y + a1.y) + (a2.y + a3.y);
    float inv = 1.0f / fmaxf((float)(end - beg), 1.0f);
    r.x *= inv; r.y *= inv;
    *(float2*)(agg + (size_t)node * D + lane * 2) = r;
}

// ---------------- helpers: in-register A split (hi/lo bf16) ----------------
#define LOAD_SPLIT_A(M1, M2, nodec, quad, ahi, alo)                              \
    {                                                                            \
        const float* m1row = (M1) + (size_t)(nodec) * D + (quad) * 8;            \
        const float* m2row = (M2) + (size_t)(nodec) * D + (quad) * 8;            \
        _Pragma("unroll")                                                        \
        for (int half = 0; half < 2; half++) {                                   \
            const float* row = half ? m2row : m1row;                             \
            _Pragma("unroll")                                                    \
            for (int ks = 0; ks < 4; ks++) {                                     \
                float4 v0 = *(const float4*)(row + ks * 32);                     \
                float4 v1 = *(const float4*)(row + ks * 32 + 4);                 \
                float vv[8] = {v0.x, v0.y, v0.z, v0.w, v1.x, v1.y, v1.z, v1.w};  \
                int idx = half * 4 + ks;                                         \
                _Pragma("unroll")                                                \
                for (int j = 0; j < 8; j++) {                                    \
                    unsigned short h = f2bf(vv[j]);                              \
                    ahi[idx][j] = (short)h;                                      \
                    alo[idx][j] = (short)f2bf(vv[j] - bf2f(h));                  \
                }                                                                \
            }                                                                    \
        }                                                                        \
    }

// ---------------- split-bf16 MFMA layer GEMM (no LDS), F_OUT=128 ----------------
// Wave = 16 nodes x 4 f-tiles; block = 32 nodes x 128 outputs. Grid = ceil(N/32).
template<bool RELU>
__global__ __launch_bounds__(256) void mfma_gemm_layer(
    const float* __restrict__ M1, const float* __restrict__ M2,
    const unsigned short* __restrict__ Whi, const unsigned short* __restrict__ Wlo,
    const float* __restrict__ bias, float* __restrict__ out)
{
    int wave = threadIdx.x >> 6, lane = threadIdx.x & 63;
    int m = lane & 15, quad = lane >> 4;
    int node_base = (blockIdx.x * 2 + (wave >> 1)) * 16;
    int tile_base = (wave & 1) * 4;
    if (node_base >= N_NODES) return;
    int nodec = min(node_base + m, N_NODES - 1);

    bf16x8 ahi[8], alo[8];
    LOAD_SPLIT_A(M1, M2, nodec, quad, ahi, alo)

    #pragma unroll
    for (int nt = 0; nt < 4; nt++) {
        int f = (tile_base + nt) * 16 + m;
        const unsigned short* whirow = Whi + (size_t)f * 256 + quad * 8;
        const unsigned short* wlorow = Wlo + (size_t)f * 256 + quad * 8;
        f32x4 acc0 = {0.f, 0.f, 0.f, 0.f};
        f32x4 acc1 = {0.f, 0.f, 0.f, 0.f};
        f32x4 acc2 = {0.f, 0.f, 0.f, 0.f};
        #pragma unroll
        for (int ks = 0; ks < 8; ks++) {
            bf16x8 bh = *(const bf16x8*)(whirow + ks * 32);
            bf16x8 bl = *(const bf16x8*)(wlorow + ks * 32);
            acc0 = __builtin_amdgcn_mfma_f32_16x16x32_bf16(ahi[ks], bh, acc0, 0, 0, 0);
            acc1 = __builtin_amdgcn_mfma_f32_16x16x32_bf16(ahi[ks], bl, acc1, 0, 0, 0);
            acc2 = __builtin_amdgcn_mfma_f32_16x16x32_bf16(alo[ks], bh, acc2, 0, 0, 0);
        }
        float bv = bias[f];
        #pragma unroll
        for (int r = 0; r < 4; r++) {
            int nrow = node_base + quad * 4 + r;
            if (nrow >= N_NODES) continue;
            float v = (acc0[r] + (acc1[r] + acc2[r])) + bv;
            if (RELU) v = fmaxf(v, 0.f);
            out[(size_t)nrow * 128 + f] = v;
        }
    }
}

// ---------------- final GEMM (F=40, padded 48) + fused log_softmax ----------------
// Wave = 16 nodes x 3 f-tiles (covers all 48 cols). Node's 40 logits live across
// the 16 lanes of its quad (<=3 per lane) -> shfl_xor reduce (masks 1,2,4,8).
__global__ __launch_bounds__(256) void mfma_final(
    const float* __restrict__ M1, const float* __restrict__ M2,
    const unsigned short* __restrict__ Whi, const unsigned short* __restrict__ Wlo,
    const float* __restrict__ bias, float* __restrict__ out)
{
    int wave = threadIdx.x >> 6, lane = threadIdx.x & 63;
    int m = lane & 15, quad = lane >> 4;
    int node_base = (blockIdx.x * 4 + wave) * 16;
    if (node_base >= N_NODES) return;
    int nodec = min(node_base + m, N_NODES - 1);

    bf16x8 ahi[8], alo[8];
    LOAD_SPLIT_A(M1, M2, nodec, quad, ahi, alo)

    float res[3][4];
    #pragma unroll
    for (int nt = 0; nt < 3; nt++) {
        int f = nt * 16 + m;
        const unsigned short* whirow = Whi + (size_t)f * 256 + quad * 8;
        const unsigned short* wlorow = Wlo + (size_t)f * 256 + quad * 8;
        f32x4 acc0 = {0.f, 0.f, 0.f, 0.f};
        f32x4 acc1 = {0.f, 0.f, 0.f, 0.f};
        f32x4 acc2 = {0.f, 0.f, 0.f, 0.f};
        #pragma unroll
        for (int ks = 0; ks < 8; ks++) {
            bf16x8 bh = *(const bf16x8*)(whirow + ks * 32);
            bf16x8 bl = *(const bf16x8*)(wlorow + ks * 32);
            acc0 = __builtin_amdgcn_mfma_f32_16x16x32_bf16(ahi[ks], bh, acc0, 0, 0, 0);
            acc1 = __builtin_amdgcn_mfma_f32_16x16x32_bf16(ahi[ks], bl, acc1, 0, 0, 0);
            acc2 = __builtin_amdgcn_mfma_f32_16x16x32_bf16(alo[ks], bh, acc2, 0, 0, 0);
        }
        float bv = (f < 40) ? bias[f] : 0.f;
        #pragma unroll
        for (int r = 0; r < 4; r++)
            res[nt][r] = (acc0[r] + (acc1[r] + acc2[r])) + bv;
    }

    // fused log-softmax per node row (reduce over 16 lanes of the quad)
    #pragma unroll
    for (int r = 0; r < 4; r++) {
        float pm = -INFINITY;
        #pragma unroll
        for (int nt = 0; nt < 3; nt++)
            if (nt * 16 + m < 40) pm = fmaxf(pm, res[nt][r]);
        #pragma unroll
        for (int o = 8; o > 0; o >>= 1) pm = fmaxf(pm, __shfl_xor(pm, o, 64));
        float ps = 0.f;
        #pragma unroll
        for (int nt = 0; nt < 3; nt++)
            if (nt * 16 + m < 40) ps += expf(res[nt][r] - pm);
        #pragma unroll
        for (int o = 8; o > 0; o >>= 1) ps += __shfl_xor(ps, o, 64);
        float lse = pm + logf(ps);
        int nrow = node_base + quad * 4 + r;
        if (nrow >= N_NODES) continue;
        #pragma unroll
        for (int nt = 0; nt < 3; nt++) {
            int f = nt * 16 + m;
            if (f < 40) out[(size_t)nrow * 40 + f] = res[nt][r] - lse;
        }
    }
}

extern "C" void kernel_launch(void* const* d_in, const int* in_sizes, int n_in,
                              void* d_out, int out_size, void* d_ws, size_t ws_size,
                              hipStream_t stream) {
    const float* x     = (const float*)d_in[0];
    const int*   ei    = (const int*)d_in[1];
    const int*   src   = ei;
    const int*   dst   = ei + N_EDGES;
    const float* W1_l  = (const float*)d_in[2];
    const float* b1_l  = (const float*)d_in[3];
    const float* W1_r  = (const float*)d_in[4];
    const float* W2_l  = (const float*)d_in[5];
    const float* b2_l  = (const float*)d_in[6];
    const float* W2_r  = (const float*)d_in[7];
    const float* W_lin = (const float*)d_in[8];
    const float* b_lin = (const float*)d_in[9];
    float* out = (float*)d_out;

    const size_t nd = (size_t)N_NODES * D;
    float* agg = (float*)d_ws;
    float* h1  = agg + nd;
    float* h2  = h1 + nd;
    unsigned short* W1hi = (unsigned short*)(h2 + nd);  // 128*256 bf16 each
    unsigned short* W1lo = W1hi + 128 * 256;
    unsigned short* W2hi = W1lo + 128 * 256;
    unsigned short* W2lo = W2hi + 128 * 256;
    unsigned short* WLhi = W2lo + 128 * 256;            // 48*256
    unsigned short* WLlo = WLhi + 48 * 256;
    int* deg    = (int*)(WLlo + 48 * 256);
    int* rowptr = deg + N_NODES;
    int* cursor = rowptr + N_NODES + 1;
    int* srcs_sorted = cursor + N_NODES;

    // ---- CSR build (reused by both layers) ----
    hipMemsetAsync(deg, 0, N_NODES * sizeof(int), stream);
    deg_kernel<<<(N_EDGES + 255) / 256, 256, 0, stream>>>(dst, deg);
    scan_kernel<<<1, 1024, 0, stream>>>(deg, rowptr, cursor);
    bucket_kernel<<<(N_EDGES + 255) / 256, 256, 0, stream>>>(src, dst, cursor, srcs_sorted);

    // ---- weight split-casts ----
    cast_cat_kernel<<<128, 128, 0, stream>>>(W1_l, W1_r, W1hi, W1lo);
    cast_cat_kernel<<<128, 128, 0, stream>>>(W2_l, W2_r, W2hi, W2lo);
    cast_wlin_kernel<<<48, 256, 0, stream>>>(W_lin, WLhi, WLlo);

    const int lblk = (N_NODES + 31) / 32;   // layer GEMM: 32 nodes/block
    const int fblk = (N_NODES + 63) / 64;   // final GEMM: 64 nodes/block

    // ---- layer 1 ----
    gather_mean<<<(N_NODES + 3) / 4, 256, 0, stream>>>(srcs_sorted, rowptr, x, agg);
    mfma_gemm_layer<true><<<lblk, 256, 0, stream>>>(agg, x, W1hi, W1lo, b1_l, h1);

    // ---- layer 2 ----
    gather_mean<<<(N_NODES + 3) / 4, 256, 0, stream>>>(srcs_sorted, rowptr, h1, agg);
    mfma_gemm_layer<true><<<lblk, 256, 0, stream>>>(agg, h1, W2hi, W2lo, b2_l, h2);

    // ---- final linear + fused log_softmax ----
    mfma_final<<<fblk, 256, 0, stream>>>(h1, h2, WLhi, WLlo, b_lin, out);
}